// Round 15
// baseline (339.618 us; speedup 1.0000x reference)
//
#include <hip/hip_runtime.h>
#include <math.h>

#define LSZ 128
#define SPITCH 136   // bf16 elems per padded row (272 B = 17*16 -> b128-aligned,
                     // 4-rows-apart strips land 16 banks apart: no 4-way conflict)
#define NCH 8
#define NLAY 16
#define LOG2E 1.4426950408889634f
#define LN2   0.6931471805599453f

typedef float f4 __attribute__((ext_vector_type(4)));
typedef float f2 __attribute__((ext_vector_type(2)));

// wave-uniform float -> SGPR
__device__ __forceinline__ float uni(float v) {
    return __uint_as_float(__builtin_amdgcn_readfirstlane(__float_as_uint(v)));
}

// unpack 2 bf16 from u32 (bf16->f32 exact)
__device__ __forceinline__ f2 unpk2(unsigned u) {
    f2 r;
    r.x = __uint_as_float(u << 16);
    r.y = __uint_as_float(u & 0xffff0000u);
    return r;
}
struct f8 { f4 a, b; };
// read 8 bf16 (one ds_read_b128) -> two f4
__device__ __forceinline__ f8 ldr8(const unsigned short* p) {
    uint4 w = *(const uint4*)p;
    f2 p0 = unpk2(w.x), p1 = unpk2(w.y), p2 = unpk2(w.z), p3 = unpk2(w.w);
    f8 r;
    r.a = (f4){p0.x, p0.y, p1.x, p1.y};
    r.b = (f4){p2.x, p2.y, p3.x, p3.y};
    return r;
}
// read 4 bf16 (one ds_read_b64) -> f4
__device__ __forceinline__ f4 ldr4(const unsigned short* p) {
    uint2 w = *(const uint2*)p;
    f2 p0 = unpk2(w.x), p1 = unpk2(w.y);
    return (f4){p0.x, p0.y, p1.x, p1.y};
}
// pack 8 f32 -> 8 bf16 RNE (v_cvt_pk_bf16_f32), one ds_write_b128
__device__ __forceinline__ void str8(unsigned short* p, f4 va, f4 vb) {
    unsigned q0, q1, q2, q3;
    asm("v_cvt_pk_bf16_f32 %0, %1, %2" : "=v"(q0) : "v"(va.x), "v"(va.y));
    asm("v_cvt_pk_bf16_f32 %0, %1, %2" : "=v"(q1) : "v"(va.z), "v"(va.w));
    asm("v_cvt_pk_bf16_f32 %0, %1, %2" : "=v"(q2) : "v"(vb.x), "v"(vb.y));
    asm("v_cvt_pk_bf16_f32 %0, %1, %2" : "=v"(q3) : "v"(vb.z), "v"(vb.w));
    *(uint4*)p = make_uint4(q0, q1, q2, q3);
}

// One block per (batch, channel) plane. 512 threads: 32 row-strips x 16
// col-groups, 4 rows x 8 cols per thread. BF16 ping-pong planes with padded
// row pitch (SPITCH=136), ~71 KB/block -> 2 blocks/CU, single barrier/layer.
// Own rows carried in f32 regs; vertical stencil accumulated over input rows.
// Uniform-shift fold: x = x~ - l; weights pre-scaled by log2e;
// CELU tail = fma(max(y',0), ln2, x~) + exp2(min(y',0)).
__global__ __launch_bounds__(512)
void plane_kernel(const float* __restrict__ nrm,   // (256,128,3)
                  const float* __restrict__ W,     // (16,8,5)
                  float* __restrict__ ws)          // (2048,) per-block sums
{
    __shared__ __align__(16) unsigned short xa[LSZ * SPITCH];   // 34816 B
    __shared__ __align__(16) unsigned short xb[LSZ * SPITCH];   // 34816 B
    __shared__ float nsm[LSZ * 3];
    __shared__ float wsm[NLAY * 5];
    __shared__ float red[8];

    const int bid = blockIdx.x;
    const int b   = bid >> 3;
    const int c   = bid & 7;
    const int tid = threadIdx.x;

    if (tid < LSZ * 3) nsm[tid] = nrm[b * (LSZ * 3) + tid];
    if (tid < NLAY * 5) {
        int l = tid / 5, d = tid % 5;
        wsm[tid] = W[l * (NCH * 5) + c * 5 + d] * LOG2E;   // pre-scaled
    }
    __syncthreads();

    const int jg = tid & 15;        // col group  -> j0 = 8*jg
    const int is = tid >> 4;        // row strip  -> i0 = 4*is
    const int j0 = jg * 8;
    const int i0 = is * 4;

    f8 own[4];   // this thread's 4 rows x 8 cols (x~ state, f32)

    // ---- init: g[i][j] = dot3(n[i], n[j]), zero diagonal ----
    {
        float njx[8], njy[8], njz[8];
#pragma unroll
        for (int q = 0; q < 8; ++q) {
            njx[q] = nsm[(j0 + q) * 3 + 0];
            njy[q] = nsm[(j0 + q) * 3 + 1];
            njz[q] = nsm[(j0 + q) * 3 + 2];
        }
#pragma unroll
        for (int k = 0; k < 4; ++k) {
            int r = i0 + k;
            float n0 = nsm[r * 3 + 0], n1 = nsm[r * 3 + 1], n2 = nsm[r * 3 + 2];
            float g[8];
#pragma unroll
            for (int q = 0; q < 8; ++q) {
                g[q] = n0 * njx[q] + n1 * njy[q] + n2 * njz[q];
                if (r == j0 + q) g[q] = 0.f;
            }
            own[k].a = (f4){g[0], g[1], g[2], g[3]};
            own[k].b = (f4){g[4], g[5], g[6], g[7]};
            str8(&xa[r * SPITCH + j0], own[k].a, own[k].b);
        }
    }
    __syncthreads();

    // LDS offsets (bf16 elements, padded pitch). Halo strips 4-row-aligned ->
    // physically contiguous rows even across the wrap.
    const int oT = ((i0 - 4) & (LSZ - 1)) * SPITCH + j0;   // rows i0-4..i0-1
    const int oB = ((i0 + 4) & (LSZ - 1)) * SPITCH + j0;   // rows i0+4..i0+7
    const int oL = i0 * SPITCH + ((j0 - 4) & (LSZ - 1));   // left 4 cols
    const int oR = i0 * SPITCH + ((j0 + 8) & (LSZ - 1));   // right 4 cols
    const int oO = i0 * SPITCH + j0;                       // own rows

    auto do_layer = [&](const unsigned short* src, unsigned short* dst, int l) {
        const float w[5] = { uni(wsm[l * 5 + 0]), uni(wsm[l * 5 + 1]),
                             uni(wsm[l * 5 + 2]), uni(wsm[l * 5 + 3]),
                             uni(wsm[l * 5 + 4]) };
        // uniform shift: entering layer l, x = x~ - l; stencil(const) = s*T
        const float sT = -(float)l * (w[0] + 4.0f * (w[1] + w[2] + w[3] + w[4]));

        f8 acc[4];

        // ---- horizontal taps + center + shift (own rows, L/R halo) ----
#pragma unroll
        for (int m = 0; m < 4; ++m) {
            const f4 A = ldr4(&src[oL + m * SPITCH]);   // cols j0-4..j0-1
            const f4 D = ldr4(&src[oR + m * SPITCH]);   // cols j0+8..j0+11
            const f4 B = own[m].a, C = own[m].b;

            f4 h1a; { f2 t = B.xy + B.zw; h1a = (f4){A.w + B.y, t.x, t.y, B.z + C.x}; }
            f4 h2a; { f2 u = A.zw + B.zw; f2 v = B.xy + C.xy; h2a = (f4){u.x, u.y, v.x, v.y}; }
            f4 h3a; { f2 t = A.zw + C.xy; h3a = (f4){A.y + B.w, t.x, t.y, B.x + C.z}; }
            f4 h4a = A + C;
            f4 h1b; { f2 t = C.xy + C.zw; h1b = (f4){B.w + C.y, t.x, t.y, C.z + D.x}; }
            f4 h2b; { f2 u = B.zw + C.zw; f2 v = C.xy + D.xy; h2b = (f4){u.x, u.y, v.x, v.y}; }
            f4 h3b; { f2 t = B.zw + D.xy; h3b = (f4){B.y + C.w, t.x, t.y, C.x + D.z}; }
            f4 h4b = B + D;

            acc[m].a = (w[0] * B + sT) + w[1] * h1a + w[2] * h2a + w[3] * h3a + w[4] * h4a;
            acc[m].b = (w[0] * C + sT) + w[1] * h1b + w[2] * h2b + w[3] * h3b + w[4] * h4b;
        }

        // ---- vertical: own rows into other own accumulators ----
#pragma unroll
        for (int k = 0; k < 4; ++k)
#pragma unroll
            for (int m = 0; m < 4; ++m)
                if (m != k) {
                    const float wd = w[(m > k) ? (m - k) : (k - m)];
                    acc[m].a += wd * own[k].a;
                    acc[m].b += wd * own[k].b;
                }

        // ---- vertical: top halo rows (i0-4+k), feed acc[0..k] ----
#pragma unroll
        for (int k = 0; k < 4; ++k) {
            f8 r = ldr8(&src[oT + k * SPITCH]);
#pragma unroll
            for (int m = 0; m <= k; ++m) {
                const float wd = w[m - k + 4];
                acc[m].a += wd * r.a;
                acc[m].b += wd * r.b;
            }
        }
        // ---- vertical: bottom halo rows (i0+4+k), feed acc[k..3] ----
#pragma unroll
        for (int k = 0; k < 4; ++k) {
            f8 r = ldr8(&src[oB + k * SPITCH]);
#pragma unroll
            for (int m = k; m < 4; ++m) {
                const float wd = w[4 + k - m];
                acc[m].a += wd * r.a;
                acc[m].b += wd * r.b;
            }
        }

        // ---- CELU tail + residual, write, carry ----
#pragma unroll
        for (int m = 0; m < 4; ++m) {
            f4 ya = acc[m].a, yb = acc[m].b;
            f4 ypa = __builtin_elementwise_max(ya, (f4)0.0f);
            f4 yna = __builtin_elementwise_min(ya, (f4)0.0f);
            f4 ypb = __builtin_elementwise_max(yb, (f4)0.0f);
            f4 ynb = __builtin_elementwise_min(yb, (f4)0.0f);
            f4 ea, eb;
            ea.x = __builtin_amdgcn_exp2f(yna.x);
            ea.y = __builtin_amdgcn_exp2f(yna.y);
            ea.z = __builtin_amdgcn_exp2f(yna.z);
            ea.w = __builtin_amdgcn_exp2f(yna.w);
            eb.x = __builtin_amdgcn_exp2f(ynb.x);
            eb.y = __builtin_amdgcn_exp2f(ynb.y);
            eb.z = __builtin_amdgcn_exp2f(ynb.z);
            eb.w = __builtin_amdgcn_exp2f(ynb.w);
            f4 ra = (ypa * LN2 + own[m].a) + ea;   // "-1" lives in the shift
            f4 rb = (ypb * LN2 + own[m].b) + eb;

            str8(&dst[oO + m * SPITCH], ra, rb);
            own[m].a = ra; own[m].b = rb;
        }
        __syncthreads();                   // single barrier per layer
    };

#pragma unroll 1
    for (int l = 0; l < NLAY; l += 2) {
        do_layer(xa, xb, l);
        do_layer(xb, xa, l + 1);
    }

    // ---- block reduction of final x~ (in own[], f32) ----
    float local = 0.f;
#pragma unroll
    for (int m = 0; m < 4; ++m) {
        f4 s = own[m].a + own[m].b;
        local += (s.x + s.y) + (s.z + s.w);
    }
#pragma unroll
    for (int off = 32; off > 0; off >>= 1)
        local += __shfl_down(local, off, 64);

    const int wave = tid >> 6;
    if ((tid & 63) == 0) red[wave] = local;
    __syncthreads();
    if (tid == 0) {
        float s = 0.f;
#pragma unroll
        for (int w = 0; w < 8; ++w) s += red[w];
        ws[bid] = s;
    }
}

__global__ void finish_kernel(const float* __restrict__ ws, float* __restrict__ out) {
    int b = threadIdx.x;
    float s = 0.f;
#pragma unroll
    for (int c = 0; c < NCH; ++c) s += ws[b * NCH + c];
    // x = x~ - 16 after all layers: mean_true = mean(x~) - 16
    out[b] = expf(16.0f - s / (8.0f * 128.0f * 128.0f));
}

extern "C" void kernel_launch(void* const* d_in, const int* in_sizes, int n_in,
                              void* d_out, int out_size, void* d_ws, size_t ws_size,
                              hipStream_t stream) {
    const float* nrm = (const float*)d_in[0];   // (256,128,3) f32
    const float* W   = (const float*)d_in[1];   // (16,8,5) f32
    float* out = (float*)d_out;                 // (256,) f32
    float* ws  = (float*)d_ws;                  // >= 2048 f32 scratch

    plane_kernel<<<dim3(256 * NCH), dim3(512), 0, stream>>>(nrm, W, ws);
    finish_kernel<<<dim3(1), dim3(256), 0, stream>>>(ws, out);
}

// Round 16
// 274.729 us; speedup vs baseline: 1.2362x; 1.2362x over previous
//
#include <hip/hip_runtime.h>
#include <math.h>

#define LSZ 128
#define NCH 8
#define NLAY 16
#define LOG2E 1.4426950408889634f
#define LN2   0.6931471805599453f

// clang ext_vector: true vector ops -> backend selects v_pk_{add,mul,fma,max,min}_f32.
typedef float f4 __attribute__((ext_vector_type(4)));
typedef float f2 __attribute__((ext_vector_type(2)));

// wave-uniform float -> SGPR
__device__ __forceinline__ float uni(float v) {
    return __uint_as_float(__builtin_amdgcn_readfirstlane(__float_as_uint(v)));
}

// One block per (batch, channel) plane. 1024 threads: 32 row-strips x 32
// col-groups, 4 rows x 4 cols per thread. TWO f32 LDS planes, ping-pong per
// layer (read A, write B) -> ONE barrier per layer and no write hazard.
// Uniform-shift fold: state stored as x~ where x = x~ - l (the celu "-1"
// accumulates uniformly); stencil contribution of the shift is s*T, folded
// into the tree as an SGPR fma addend. Weights pre-scaled by log2e;
// CELU tail = fma(max(y',0), ln2, x~) + exp2(min(y',0)).
// [Best-measured config across 16 rounds: 274 us bench / ~315 us prof.
//  Falsified alternatives: bf16 planes (unpack latency tax + intrinsic
//  bank conflicts), in-place + 2 barriers (~790 cyc drain each), padded
//  pitch (conflicts worsened, lost co-residency), 1024-thr co-residency
//  (never schedules 2nd block), register-attr forcing (allocator ignores).]
__global__ __launch_bounds__(1024)
void plane_kernel(const float* __restrict__ nrm,   // (256,128,3)
                  const float* __restrict__ W,     // (16,8,5)
                  float* __restrict__ ws)          // (2048,) per-block sums
{
    __shared__ float xa[LSZ * LSZ];    // 65536 B
    __shared__ float xb[LSZ * LSZ];    // 65536 B
    __shared__ float nsm[LSZ * 3];
    __shared__ float wsm[NLAY * 5];
    __shared__ float red[16];

    const int bid = blockIdx.x;
    const int b   = bid >> 3;
    const int c   = bid & 7;
    const int tid = threadIdx.x;

    if (tid < LSZ * 3) nsm[tid] = nrm[b * (LSZ * 3) + tid];
    if (tid < NLAY * 5) {
        int l = tid / 5, d = tid % 5;
        wsm[tid] = W[l * (NCH * 5) + c * 5 + d] * LOG2E;   // pre-scaled
    }
    __syncthreads();

    const int jg = tid & 31;        // col group  -> j0 = 4*jg
    const int is = tid >> 5;        // row strip  -> i0 = 4*is
    const int j0 = jg * 4;
    const int i0 = is * 4;

    f4 own[4];   // this thread's 4 rows (x~ state, carried in registers)

    // ---- init: g[i][j] = dot3(n[i], n[j]), zero diagonal (s_0 = 0) ----
    {
        float nj0x = nsm[(j0 + 0) * 3 + 0], nj0y = nsm[(j0 + 0) * 3 + 1], nj0z = nsm[(j0 + 0) * 3 + 2];
        float nj1x = nsm[(j0 + 1) * 3 + 0], nj1y = nsm[(j0 + 1) * 3 + 1], nj1z = nsm[(j0 + 1) * 3 + 2];
        float nj2x = nsm[(j0 + 2) * 3 + 0], nj2y = nsm[(j0 + 2) * 3 + 1], nj2z = nsm[(j0 + 2) * 3 + 2];
        float nj3x = nsm[(j0 + 3) * 3 + 0], nj3y = nsm[(j0 + 3) * 3 + 1], nj3z = nsm[(j0 + 3) * 3 + 2];
#pragma unroll
        for (int k = 0; k < 4; ++k) {
            int r = i0 + k;
            float n0 = nsm[r * 3 + 0], n1 = nsm[r * 3 + 1], n2 = nsm[r * 3 + 2];
            float g0 = n0 * nj0x + n1 * nj0y + n2 * nj0z;
            float g1 = n0 * nj1x + n1 * nj1y + n2 * nj1z;
            float g2 = n0 * nj2x + n1 * nj2y + n2 * nj2z;
            float g3 = n0 * nj3x + n1 * nj3y + n2 * nj3z;
            if (r == j0 + 0) g0 = 0.f;
            if (r == j0 + 1) g1 = 0.f;
            if (r == j0 + 2) g2 = 0.f;
            if (r == j0 + 3) g3 = 0.f;
            f4 v = (f4){g0, g1, g2, g3};
            *(f4*)&xa[r * LSZ + j0] = v;
            own[k] = v;
        }
    }
    __syncthreads();

    // LDS offsets (elements). 4-row halo groups are whole neighbor strips ->
    // contiguous even across wrap. Row offsets k*LSZ -> ds_read immediates.
    const int oT = ((i0 - 4) & (LSZ - 1)) * LSZ + j0;   // top halo strip
    const int oB = ((i0 + 4) & (LSZ - 1)) * LSZ + j0;   // bottom halo strip
    const int oL = i0 * LSZ + ((j0 - 4) & (LSZ - 1));   // left cols
    const int oR = i0 * LSZ + ((j0 + 4) & (LSZ - 1));   // right cols
    const int oO = i0 * LSZ + j0;                       // own rows

    auto do_layer = [&](const float* src, float* dst, int l) {
        const float w0 = uni(wsm[l * 5 + 0]);
        const float w1 = uni(wsm[l * 5 + 1]);
        const float w2 = uni(wsm[l * 5 + 2]);
        const float w3 = uni(wsm[l * 5 + 3]);
        const float w4 = uni(wsm[l * 5 + 4]);
        // uniform shift: entering layer l, x = x~ - l; stencil(const) = s*T
        const float sT = -(float)l * (w0 + 4.0f * (w1 + w2 + w3 + w4));

        f4 t[4], bo[4], res[4];
#pragma unroll
        for (int k = 0; k < 4; ++k) {
            t[k]  = *(const f4*)&src[oT + k * LSZ];
            bo[k] = *(const f4*)&src[oB + k * LSZ];
        }

        // VV(k): vertical stack rows i0-4+k, k = 0..11
#define VV(k) ((k) < 4 ? t[(k)] : (k) < 8 ? own[(k) - 4] : bo[(k) - 8])

        f4 Lc = *(const f4*)&src[oL];
        f4 Rc = *(const f4*)&src[oR];
#pragma unroll
        for (int m = 0; m < 4; ++m) {
            f4 Ln, Rn;
            if (m < 3) {
                Ln = *(const f4*)&src[oL + (m + 1) * LSZ];
                Rn = *(const f4*)&src[oR + (m + 1) * LSZ];
            }
            const f4 C = own[m];

            // horizontal shifted-pair taps (pk-pair structured)
            f2 h1m = C.xy + C.zw;                      // {C.x+C.z, C.y+C.w}
            f4 h1 = (f4){Lc.w + C.y, h1m.x, h1m.y, C.z + Rc.x};
            f2 h2a = Lc.zw + C.zw;                     // {Lc.z+C.z, Lc.w+C.w}
            f2 h2b = C.xy + Rc.xy;                     // {C.x+Rc.x, C.y+Rc.y}
            f4 h2 = (f4){h2a.x, h2a.y, h2b.x, h2b.y};
            f2 h3m = Lc.zw + Rc.xy;                    // {Lc.z+Rc.x, Lc.w+Rc.y}
            f4 h3 = (f4){Lc.y + C.w, h3m.x, h3m.y, C.x + Rc.z};
            f4 h4 = Lc + Rc;

            // y' = y * log2e (weights pre-scaled); sT folds into the first fma
            f4 y = (w0 * C + sT)
                 + w1 * (h1 + (VV(m + 3) + VV(m + 5)))
                 + w2 * (h2 + (VV(m + 2) + VV(m + 6)))
                 + w3 * (h3 + (VV(m + 1) + VV(m + 7)))
                 + w4 * (h4 + (VV(m + 0) + VV(m + 8)));

            f4 yp = __builtin_elementwise_max(y, (f4)0.0f);
            f4 yn = __builtin_elementwise_min(y, (f4)0.0f);
            f4 e2;
            e2.x = __builtin_amdgcn_exp2f(yn.x);
            e2.y = __builtin_amdgcn_exp2f(yn.y);
            e2.z = __builtin_amdgcn_exp2f(yn.z);
            e2.w = __builtin_amdgcn_exp2f(yn.w);
            f4 r = (yp * LN2 + C) + e2;    // x~_next ("-1" lives in the shift)

            *(f4*)&dst[oO + m * LSZ] = r;  // write immediately (plane B unread)
            res[m] = r;

            Lc = Ln; Rc = Rn;
        }
#undef VV
#pragma unroll
        for (int m = 0; m < 4; ++m) own[m] = res[m];
        __syncthreads();                   // single barrier per layer
    };

#pragma unroll 1
    for (int l = 0; l < NLAY; l += 2) {
        do_layer(xa, xb, l);
        do_layer(xb, xa, l + 1);
    }

    // ---- per-block sum of final plane (x~ in own[0..3]) ----
    float local = 0.f;
#pragma unroll
    for (int m = 0; m < 4; ++m)
        local += own[m].x + own[m].y + own[m].z + own[m].w;

#pragma unroll
    for (int off = 32; off > 0; off >>= 1)
        local += __shfl_down(local, off, 64);

    const int wave = tid >> 6;
    if ((tid & 63) == 0) red[wave] = local;
    __syncthreads();
    if (tid == 0) {
        float s = 0.f;
#pragma unroll
        for (int w = 0; w < 16; ++w) s += red[w];
        ws[bid] = s;
    }
}

__global__ void finish_kernel(const float* __restrict__ ws, float* __restrict__ out) {
    int b = threadIdx.x;
    float s = 0.f;
#pragma unroll
    for (int c = 0; c < NCH; ++c) s += ws[b * NCH + c];
    // x = x~ - 16 after all layers: mean_true = mean(x~) - 16
    out[b] = expf(16.0f - s / (8.0f * 128.0f * 128.0f));
}

extern "C" void kernel_launch(void* const* d_in, const int* in_sizes, int n_in,
                              void* d_out, int out_size, void* d_ws, size_t ws_size,
                              hipStream_t stream) {
    const float* nrm = (const float*)d_in[0];   // (256,128,3) f32
    const float* W   = (const float*)d_in[1];   // (16,8,5) f32
    float* out = (float*)d_out;                 // (256,) f32
    float* ws  = (float*)d_ws;                  // >= 2048 f32 scratch

    plane_kernel<<<dim3(256 * NCH), dim3(1024), 0, stream>>>(nrm, W, ws);
    finish_kernel<<<dim3(1), dim3(256), 0, stream>>>(ws, out);
}